// Round 4
// baseline (114.466 us; speedup 1.0000x reference)
//
#include <hip/hip_runtime.h>
#include <float.h>

#define BATCH 128
#define IMS   64
#define NPIX  4096      // 64*64
#define LQ    10
#define LH    150
#define NACT  8
#define TROWS 16        // tile rows per block in k_main

// ---- output layout (floats) ----
#define OUT_Q       0
#define OUT_LOGITS  (BATCH*LQ*NPIX)            // 5242880
#define OUT_ACTION  (OUT_LOGITS + BATCH*NACT)  // 5243904

// Kernel A: fused  [collapse h,r weights] -> r tile in LDS -> q0 -> out.q
// One block = one 16-row tile of one image. 512 blocks.
__global__ __launch_bounds__(256) void k_main(const float* __restrict__ in,
                                              const float* __restrict__ h_w,
                                              const float* __restrict__ h_b,
                                              const float* __restrict__ r_w,
                                              const float* __restrict__ q_w,
                                              float* __restrict__ out) {
    const int blk  = blockIdx.x;
    const int b    = blk >> 2;          // image index
    const int tile = blk & 3;
    const int r0   = tile * TROWS;      // first output row of this tile
    const int t    = threadIdx.x;

    __shared__ float cf[20];            // 18 collapsed conv weights + bias
    __shared__ float qw[96];            // q_w (90 floats)
    __shared__ float rt[TROWS + 2][IMS];// r rows r0-1 .. r0+TROWS (zero outside img)

    // collapse the 150-channel hidden layer:  rw_eff[t] = sum_c r_w[c]*h_w[c,t]
    if (t < 19) {
        float s = 0.f;
        if (t < 18) {
            for (int c = 0; c < LH; ++c) s += r_w[c] * h_w[c * 18 + t];
        } else {
            for (int c = 0; c < LH; ++c) s += r_w[c] * h_b[c];
        }
        cf[t] = s;
    }
    if (t >= 32 && t < 32 + LQ * 9) qw[t - 32] = q_w[t - 32];
    __syncthreads();

    const float* in0 = in + (size_t)b * 2 * NPIX;
    const float bias = cf[18];

    // r tile (incl. 1-row halo top+bottom), computed straight from input
    for (int p = t; p < (TROWS + 2) * IMS; p += 256) {
        int li = p >> 6;                // LDS row 0..TROWS+1
        int j  = p & 63;
        int i  = r0 - 1 + li;           // global row, -1..64
        float acc = 0.f;
        if (i >= 0 && i < IMS) {
            acc = bias;
#pragma unroll
            for (int c = 0; c < 2; ++c)
#pragma unroll
                for (int di = 0; di < 3; ++di) {
                    int y = i + di - 1;
                    if (y < 0 || y >= IMS) continue;
#pragma unroll
                    for (int dj = 0; dj < 3; ++dj) {
                        int x = j + dj - 1;
                        if (x < 0 || x >= IMS) continue;
                        acc += in0[c * NPIX + y * IMS + x] * cf[c * 9 + di * 3 + dj];
                    }
                }
        }
        rt[li][j] = acc;                // rows outside image stay 0 (conv zero-pad)
    }
    __syncthreads();

    // q0 = conv3x3(r, q_w) for this tile's TROWS*64 pixels
#pragma unroll
    for (int s = 0; s < (TROWS * IMS) / 256; ++s) {
        int p  = s * 256 + t;
        int lr = (p >> 6) + 1;          // LDS row of the pixel
        int j  = p & 63;
        int gi = r0 + (p >> 6);
        float nb[9];
#pragma unroll
        for (int di = 0; di < 3; ++di)
#pragma unroll
            for (int dj = 0; dj < 3; ++dj) {
                int x = j + dj - 1;
                nb[di * 3 + dj] = (x < 0 || x >= IMS) ? 0.f : rt[lr + di - 1][x];
            }
        float* qb = out + OUT_Q + (size_t)b * LQ * NPIX + gi * IMS + j;
#pragma unroll
        for (int c = 0; c < LQ; ++c) {
            float acc = 0.f;
#pragma unroll
            for (int u = 0; u < 9; ++u) acc += nb[u] * qw[c * 9 + u];
            qb[c * NPIX] = acc;         // lane-consecutive -> coalesced
        }
    }
}

// Kernel B: value-iteration + final q-update, one block per image.
// Self-computes the w==0 flag and early-exits uniformly (q already = q0 = fixed point).
__global__ __launch_bounds__(256) void k_iter(float* __restrict__ out,
                                              const float* __restrict__ w,
                                              const int* __restrict__ kptr) {
    __shared__ float wsh[LQ * 9];
    __shared__ float v[IMS][IMS];
    const int b = blockIdx.x, t = threadIdx.x;
    if (t < LQ * 9) wsh[t] = w[t];
    __syncthreads();
    float nz = 0.f;
    for (int i = 0; i < LQ * 9; ++i) nz += fabsf(wsh[i]);
    if (nz == 0.f) return;              // uniform across grid

    float* q0 = out + OUT_Q + (size_t)b * LQ * NPIX;
    // initial v = max_c q0  (q currently holds q0)
    for (int p = t; p < NPIX; p += 256) {
        float m = -FLT_MAX;
#pragma unroll
        for (int c = 0; c < LQ; ++c) m = fmaxf(m, q0[c * NPIX + p]);
        v[p >> 6][p & 63] = m;
    }
    __syncthreads();
    const int k = *kptr;
    for (int it = 0; it < k - 1; ++it) {
        float nv[16];
#pragma unroll
        for (int s = 0; s < 16; ++s) {
            int p = s * 256 + t;
            int i = p >> 6, j = p & 63;
            float nb[9];
#pragma unroll
            for (int di = 0; di < 3; ++di)
#pragma unroll
                for (int dj = 0; dj < 3; ++dj) {
                    int y = i + di - 1, x = j + dj - 1;
                    nb[di * 3 + dj] = (y < 0 || y >= IMS || x < 0 || x >= IMS)
                                          ? 0.f : v[y][x];
                }
            float m = -FLT_MAX;
#pragma unroll
            for (int c = 0; c < LQ; ++c) {
                float acc = q0[c * NPIX + p];
#pragma unroll
                for (int u = 0; u < 9; ++u) acc += nb[u] * wsh[c * 9 + u];
                m = fmaxf(m, acc);
            }
            nv[s] = m;
        }
        __syncthreads();
#pragma unroll
        for (int s = 0; s < 16; ++s) {
            int p = s * 256 + t;
            v[p >> 6][p & 63] = nv[s];
        }
        __syncthreads();
    }
    // fused final: q += conv3x3(v, w)
#pragma unroll
    for (int s = 0; s < 16; ++s) {
        int p = s * 256 + t;
        int i = p >> 6, j = p & 63;
        float nb[9];
#pragma unroll
        for (int di = 0; di < 3; ++di)
#pragma unroll
            for (int dj = 0; dj < 3; ++dj) {
                int y = i + di - 1, x = j + dj - 1;
                nb[di * 3 + dj] = (y < 0 || y >= IMS || x < 0 || x >= IMS)
                                      ? 0.f : v[y][x];
            }
#pragma unroll
        for (int c = 0; c < LQ; ++c) {
            float acc = q0[c * NPIX + p];
#pragma unroll
            for (int u = 0; u < 9; ++u) acc += nb[u] * wsh[c * 9 + u];
            q0[c * NPIX + p] = acc;
        }
    }
}

// Kernel C: gather q at (state_x, state_y), FC -> logits, flat argmax -> action.
__global__ void k_head(const float* __restrict__ out_q, const int* __restrict__ sx,
                       const int* __restrict__ sy, const float* __restrict__ fc_w,
                       float* __restrict__ out) {
    __shared__ float bv[BATCH];
    __shared__ int bi[BATCH];
    int t = threadIdx.x;   // 128 threads
    if (t < BATCH) {
        int x = sx[t], y = sy[t];
        float qv[LQ];
#pragma unroll
        for (int c = 0; c < LQ; ++c)
            qv[c] = out_q[OUT_Q + ((size_t)t * LQ + c) * NPIX + x * IMS + y];
        float best = -FLT_MAX;
        int bidx = 0;
#pragma unroll
        for (int a = 0; a < NACT; ++a) {
            float s = 0.f;
#pragma unroll
            for (int c = 0; c < LQ; ++c) s += qv[c] * fc_w[a * LQ + c];
            out[OUT_LOGITS + t * NACT + a] = s;
            if (s > best) { best = s; bidx = t * NACT + a; }  // strict > = first index
        }
        bv[t] = best;
        bi[t] = bidx;
    }
    __syncthreads();
    if (t == 0) {
        float mb = bv[0];
        int mi = bi[0];
        for (int u = 1; u < BATCH; ++u)
            if (bv[u] > mb) { mb = bv[u]; mi = bi[u]; }
        out[OUT_ACTION] = (float)mi;
    }
}

extern "C" void kernel_launch(void* const* d_in, const int* in_sizes, int n_in,
                              void* d_out, int out_size, void* d_ws, size_t ws_size,
                              hipStream_t stream) {
    const float* input = (const float*)d_in[0];
    const int*   sx    = (const int*)d_in[1];
    const int*   sy    = (const int*)d_in[2];
    const int*   kptr  = (const int*)d_in[3];
    const float* h_w   = (const float*)d_in[4];
    const float* h_b   = (const float*)d_in[5];
    const float* r_w   = (const float*)d_in[6];
    const float* q_w   = (const float*)d_in[7];
    const float* w     = (const float*)d_in[8];
    const float* fc_w  = (const float*)d_in[9];
    float* out = (float*)d_out;
    (void)d_ws; (void)ws_size;

    k_main<<<BATCH * (IMS / TROWS), 256, 0, stream>>>(input, h_w, h_b, r_w, q_w, out);
    k_iter<<<BATCH, 256, 0, stream>>>(out, w, kptr);
    k_head<<<1, 128, 0, stream>>>(out, sx, sy, fc_w, out);
}

// Round 6
// 112.678 us; speedup vs baseline: 1.0159x; 1.0159x over previous
//
#include <hip/hip_runtime.h>
#include <float.h>

#define BATCH 128
#define IMS   64
#define NPIX  4096      // 64*64
#define LQ    10
#define LH    150
#define NACT  8
#define TROWS 16        // tile rows per block in k_main

// ---- output layout (floats) ----
#define OUT_Q       0
#define OUT_LOGITS  (BATCH*LQ*NPIX)            // 5242880
#define OUT_ACTION  (OUT_LOGITS + BATCH*NACT)  // 5243904

// Kernel A: fused  [collapse h,r weights] -> r tile in LDS -> q0 -> out.q
// Also: the block owning image b's state pixel computes logits (valid when w==0).
__global__ __launch_bounds__(256) void k_main(const float* __restrict__ in,
                                              const float* __restrict__ h_w,
                                              const float* __restrict__ h_b,
                                              const float* __restrict__ r_w,
                                              const float* __restrict__ q_w,
                                              const int* __restrict__ sx,
                                              const int* __restrict__ sy,
                                              const float* __restrict__ fc_w,
                                              float* __restrict__ out) {
    const int blk  = blockIdx.x;
    const int b    = blk >> 2;          // image index
    const int tile = blk & 3;
    const int r0   = tile * TROWS;      // first output row of this tile
    const int t    = threadIdx.x;

    __shared__ float cf[20];            // 18 collapsed conv weights + bias
    __shared__ float qw[96];            // q_w (90 floats)
    __shared__ float rt[TROWS + 2][IMS];// r rows r0-1 .. r0+TROWS (zero outside img)

    // collapse the 150-channel hidden layer:  rw_eff[t] = sum_c r_w[c]*h_w[c,t]
    if (t < 19) {
        float s = 0.f;
        if (t < 18) {
            for (int c = 0; c < LH; ++c) s += r_w[c] * h_w[c * 18 + t];
        } else {
            for (int c = 0; c < LH; ++c) s += r_w[c] * h_b[c];
        }
        cf[t] = s;
    }
    if (t >= 32 && t < 32 + LQ * 9) qw[t - 32] = q_w[t - 32];
    __syncthreads();

    const float* in0 = in + (size_t)b * 2 * NPIX;
    const float bias = cf[18];
    const int sxb = sx[b], syb = sy[b];

    // r tile (incl. 1-row halo top+bottom), computed straight from input
    for (int p = t; p < (TROWS + 2) * IMS; p += 256) {
        int li = p >> 6;                // LDS row 0..TROWS+1
        int j  = p & 63;
        int i  = r0 - 1 + li;           // global row, -1..64
        float acc = 0.f;
        if (i >= 0 && i < IMS) {
            acc = bias;
#pragma unroll
            for (int c = 0; c < 2; ++c)
#pragma unroll
                for (int di = 0; di < 3; ++di) {
                    int y = i + di - 1;
                    if (y < 0 || y >= IMS) continue;
#pragma unroll
                    for (int dj = 0; dj < 3; ++dj) {
                        int x = j + dj - 1;
                        if (x < 0 || x >= IMS) continue;
                        acc += in0[c * NPIX + y * IMS + x] * cf[c * 9 + di * 3 + dj];
                    }
                }
        }
        rt[li][j] = acc;                // rows outside image stay 0 (conv zero-pad)
    }
    __syncthreads();

    // q0 = conv3x3(r, q_w) for this tile's TROWS*64 pixels
#pragma unroll
    for (int s = 0; s < (TROWS * IMS) / 256; ++s) {
        int p  = s * 256 + t;
        int lr = (p >> 6) + 1;          // LDS row of the pixel
        int j  = p & 63;
        int gi = r0 + (p >> 6);
        float nb[9];
#pragma unroll
        for (int di = 0; di < 3; ++di)
#pragma unroll
            for (int dj = 0; dj < 3; ++dj) {
                int x = j + dj - 1;
                nb[di * 3 + dj] = (x < 0 || x >= IMS) ? 0.f : rt[lr + di - 1][x];
            }
        float* qb = out + OUT_Q + (size_t)b * LQ * NPIX + gi * IMS + j;
        float qv[LQ];
#pragma unroll
        for (int c = 0; c < LQ; ++c) {
            float acc = 0.f;
#pragma unroll
            for (int u = 0; u < 9; ++u) acc += nb[u] * qw[c * 9 + u];
            qb[c * NPIX] = acc;         // lane-consecutive -> coalesced
            qv[c] = acc;
        }
        // FC head for the state pixel (final when w==0; k_iter overwrites otherwise)
        if (gi == sxb && j == syb) {
#pragma unroll
            for (int a = 0; a < NACT; ++a) {
                float s2 = 0.f;
#pragma unroll
                for (int c = 0; c < LQ; ++c) s2 += qv[c] * fc_w[a * LQ + c];
                out[OUT_LOGITS + b * NACT + a] = s2;
            }
        }
    }
}

// Kernel B: value-iteration + final q-update + logits, one block per image.
// Self-computes the w==0 flag and early-exits uniformly (q = q0 is the fixed point).
__global__ __launch_bounds__(256) void k_iter(float* __restrict__ out,
                                              const float* __restrict__ w,
                                              const int* __restrict__ kptr,
                                              const int* __restrict__ sx,
                                              const int* __restrict__ sy,
                                              const float* __restrict__ fc_w) {
    __shared__ float wsh[LQ * 9];
    __shared__ float v[IMS][IMS];
    const int b = blockIdx.x, t = threadIdx.x;
    if (t < LQ * 9) wsh[t] = w[t];
    __syncthreads();
    float nz = 0.f;
    for (int i = 0; i < LQ * 9; ++i) nz += fabsf(wsh[i]);
    if (nz == 0.f) return;              // uniform across grid

    float* q0 = out + OUT_Q + (size_t)b * LQ * NPIX;
    // initial v = max_c q0  (q currently holds q0)
    for (int p = t; p < NPIX; p += 256) {
        float m = -FLT_MAX;
#pragma unroll
        for (int c = 0; c < LQ; ++c) m = fmaxf(m, q0[c * NPIX + p]);
        v[p >> 6][p & 63] = m;
    }
    __syncthreads();
    const int k = *kptr;
    for (int it = 0; it < k - 1; ++it) {
        float nv[16];
#pragma unroll
        for (int s = 0; s < 16; ++s) {
            int p = s * 256 + t;
            int i = p >> 6, j = p & 63;
            float nb[9];
#pragma unroll
            for (int di = 0; di < 3; ++di)
#pragma unroll
                for (int dj = 0; dj < 3; ++dj) {
                    int y = i + di - 1, x = j + dj - 1;
                    nb[di * 3 + dj] = (y < 0 || y >= IMS || x < 0 || x >= IMS)
                                          ? 0.f : v[y][x];
                }
            float m = -FLT_MAX;
#pragma unroll
            for (int c = 0; c < LQ; ++c) {
                float acc = q0[c * NPIX + p];
#pragma unroll
                for (int u = 0; u < 9; ++u) acc += nb[u] * wsh[c * 9 + u];
                m = fmaxf(m, acc);
            }
            nv[s] = m;
        }
        __syncthreads();
#pragma unroll
        for (int s = 0; s < 16; ++s) {
            int p = s * 256 + t;
            v[p >> 6][p & 63] = nv[s];
        }
        __syncthreads();
    }
    // fused final: q += conv3x3(v, w)
#pragma unroll
    for (int s = 0; s < 16; ++s) {
        int p = s * 256 + t;
        int i = p >> 6, j = p & 63;
        float nb[9];
#pragma unroll
        for (int di = 0; di < 3; ++di)
#pragma unroll
            for (int dj = 0; dj < 3; ++dj) {
                int y = i + di - 1, x = j + dj - 1;
                nb[di * 3 + dj] = (y < 0 || y >= IMS || x < 0 || x >= IMS)
                                      ? 0.f : v[y][x];
            }
#pragma unroll
        for (int c = 0; c < LQ; ++c) {
            float acc = q0[c * NPIX + p];
#pragma unroll
            for (int u = 0; u < 9; ++u) acc += nb[u] * wsh[c * 9 + u];
            q0[c * NPIX + p] = acc;
        }
    }
    __syncthreads();
    // recompute logits for this image from the updated q (L2-resident)
    if (t < NACT) {
        int sp = sx[b] * IMS + sy[b];
        float s2 = 0.f;
#pragma unroll
        for (int c = 0; c < LQ; ++c) s2 += q0[c * NPIX + sp] * fc_w[t * LQ + c];
        out[OUT_LOGITS + b * NACT + t] = s2;
    }
}

// Kernel C: flat argmax over the 1024 logits (first-index tiebreak).
__global__ void k_argmax(float* __restrict__ out) {
    __shared__ float bv[BATCH];
    __shared__ int bi[BATCH];
    int t = threadIdx.x;   // 128 threads, one image each
    if (t < BATCH) {
        float best = -FLT_MAX;
        int bidx = 0;
#pragma unroll
        for (int a = 0; a < NACT; ++a) {
            float vv = out[OUT_LOGITS + t * NACT + a];
            if (vv > best) { best = vv; bidx = t * NACT + a; }  // strict > = first idx
        }
        bv[t] = best;
        bi[t] = bidx;
    }
    __syncthreads();
    if (t == 0) {
        float mb = bv[0];
        int mi = bi[0];
        for (int u = 1; u < BATCH; ++u)
            if (bv[u] > mb) { mb = bv[u]; mi = bi[u]; }
        out[OUT_ACTION] = (float)mi;
    }
}

extern "C" void kernel_launch(void* const* d_in, const int* in_sizes, int n_in,
                              void* d_out, int out_size, void* d_ws, size_t ws_size,
                              hipStream_t stream) {
    const float* input = (const float*)d_in[0];
    const int*   sx    = (const int*)d_in[1];
    const int*   sy    = (const int*)d_in[2];
    const int*   kptr  = (const int*)d_in[3];
    const float* h_w   = (const float*)d_in[4];
    const float* h_b   = (const float*)d_in[5];
    const float* r_w   = (const float*)d_in[6];
    const float* q_w   = (const float*)d_in[7];
    const float* w     = (const float*)d_in[8];
    const float* fc_w  = (const float*)d_in[9];
    float* out = (float*)d_out;
    (void)d_ws; (void)ws_size;

    k_main  <<<BATCH * (IMS / TROWS), 256, 0, stream>>>(input, h_w, h_b, r_w, q_w,
                                                        sx, sy, fc_w, out);
    k_iter  <<<BATCH, 256, 0, stream>>>(out, w, kptr, sx, sy, fc_w);
    k_argmax<<<1, 128, 0, stream>>>(out);
}